// Round 4
// baseline (93.059 us; speedup 1.0000x reference)
//
#include <hip/hip_runtime.h>

#define EMBD 768
#define HS 64
#define S_LEN 4096
#define QB 32
#define BK 64

typedef __attribute__((ext_vector_type(8))) short short8;
typedef __attribute__((ext_vector_type(4))) short short4_t;
typedef __attribute__((ext_vector_type(4))) float f32x4;
typedef unsigned short ushort_t;
typedef unsigned int uint_t;

static __device__ __forceinline__ ushort_t f2bf(float f) {
    union { float f; unsigned u; } x; x.f = f;
    unsigned r = x.u + 0x7fffu + ((x.u >> 16) & 1u);   // RNE
    return (ushort_t)(r >> 16);
}

static __device__ __forceinline__ uint_t cvt_pk_bf16(float lo, float hi) {
    uint_t r;
    asm volatile("v_cvt_pk_bf16_f32 %0, %1, %2" : "=v"(r) : "v"(lo), "v"(hi));
    return r;
}

// ---------------- W prep: Wt[192][768] bf16, Wt[c][k] = W_sel[k][c%64] ----------------
// Coalesced read (W row-major) -> LDS transpose -> coalesced write (Wt row-major).
__global__ __launch_bounds__(256) void wprep_kernel(
    const float* __restrict__ Wq, const float* __restrict__ Wk, const float* __restrict__ Wv,
    ushort_t* __restrict__ Wt)
{
    __shared__ float ws[64][65];
    const int blk  = blockIdx.x;           // 36 = 3 W x 12 k-blocks
    const int widx = blk / 12, kblk = blk % 12;
    const float* W = (widx == 0) ? Wq : (widx == 1) ? Wk : Wv;
    const int k0 = kblk * 64;
    const int t  = threadIdx.x;
    const int r  = t >> 2, c0 = (t & 3) * 16;
#pragma unroll
    for (int i = 0; i < 4; ++i) {
        float4 v = *(const float4*)(W + (size_t)(k0 + r) * HS + c0 + i * 4);
        ws[c0 + i*4 + 0][r] = v.x; ws[c0 + i*4 + 1][r] = v.y;
        ws[c0 + i*4 + 2][r] = v.z; ws[c0 + i*4 + 3][r] = v.w;
    }
    __syncthreads();
    const int c = t >> 2, kc = (t & 3) * 16;
    ushort_t* dst = Wt + (size_t)(widx * 64 + c) * EMBD + k0 + kc;
#pragma unroll
    for (int i = 0; i < 4; ++i) {
        short4_t p = {(short)f2bf(ws[c][kc + i*4 + 0]), (short)f2bf(ws[c][kc + i*4 + 1]),
                      (short)f2bf(ws[c][kc + i*4 + 2]), (short)f2bf(ws[c][kc + i*4 + 3])};
        *(short4_t*)(dst + i * 4) = p;
    }
}

// ---------------- QKV projection via MFMA (B-fragments register-prefetched) ----------------
__global__ __launch_bounds__(512, 4) void qkv_kernel(
    const float* __restrict__ x, const ushort_t* __restrict__ Wt,
    ushort_t* __restrict__ Qg, ushort_t* __restrict__ Kg, ushort_t* __restrict__ Vtg)
{
    __shared__ char xsb[2][32 * 128];          // [32 rows][64 k] bf16, swizzled
    __shared__ float Vs[32][65];               // V transpose buffer (padded)
    const int t    = threadIdx.x;
    const int w    = t >> 6;
    const int lane = t & 63;
    const int l15  = lane & 15;
    const int l4   = lane >> 4;
    const int mg   = w >> 2;                   // row-group 0/1
    const int cg   = w & 3;                    // col-group 0..3
    const int row0 = blockIdx.x * 32;

    const int srow  = t >> 4;
    const int wbyte = srow * 128 + (((t & 15) * 8) ^ ((srow & 7) << 4));
    const float4* xsrc4 = (const float4*)(x + (size_t)(row0 + srow) * EMBD) + (t & 15);

    const int arow  = mg * 16 + l15;
    const int abase = arow * 128;
    const int asw   = (arow & 7) << 4;

    const ushort_t* wp0 = Wt + (size_t)(cg * 16 + l15) * EMBD + l4 * 8;
    const ushort_t* wp1 = wp0 + (size_t)64 * EMBD;
    const ushort_t* wp2 = wp0 + (size_t)128 * EMBD;

    f32x4 acc0 = (f32x4){0.f,0.f,0.f,0.f}, acc1 = acc0, acc2 = acc0;
    short8 breg[2][3][2];

    // prologue: stage x tile 0, load B-frags for kt 0
    {
        float4 xv = xsrc4[0];
        short4_t p = {(short)f2bf(xv.x), (short)f2bf(xv.y), (short)f2bf(xv.z), (short)f2bf(xv.w)};
        *(short4_t*)(xsb[0] + wbyte) = p;
    }
#pragma unroll
    for (int ks = 0; ks < 2; ++ks) {
        breg[0][0][ks] = *(const short8*)(wp0 + ks * 32);
        breg[0][1][ks] = *(const short8*)(wp1 + ks * 32);
        breg[0][2][ks] = *(const short8*)(wp2 + ks * 32);
    }

#pragma unroll
    for (int kt = 0; kt < 12; ++kt) {
        const int cur = kt & 1;
        __syncthreads();
        float4 xnext;
        if (kt < 11) {
            xnext = xsrc4[(kt + 1) * 16];
            const int ko = (kt + 1) * 64;
#pragma unroll
            for (int ks = 0; ks < 2; ++ks) {
                breg[cur ^ 1][0][ks] = *(const short8*)(wp0 + ko + ks * 32);
                breg[cur ^ 1][1][ks] = *(const short8*)(wp1 + ko + ks * 32);
                breg[cur ^ 1][2][ks] = *(const short8*)(wp2 + ko + ks * 32);
            }
        }
#pragma unroll
        for (int ks = 0; ks < 2; ++ks) {
            short8 af = *(const short8*)(xsb[cur] + abase + ((ks * 64 + l4 * 16) ^ asw));
            acc0 = __builtin_amdgcn_mfma_f32_16x16x32_bf16(af, breg[cur][0][ks], acc0, 0, 0, 0);
            acc1 = __builtin_amdgcn_mfma_f32_16x16x32_bf16(af, breg[cur][1][ks], acc1, 0, 0, 0);
            acc2 = __builtin_amdgcn_mfma_f32_16x16x32_bf16(af, breg[cur][2][ks], acc2, 0, 0, 0);
        }
        if (kt < 11) {
            short4_t p = {(short)f2bf(xnext.x), (short)f2bf(xnext.y), (short)f2bf(xnext.z), (short)f2bf(xnext.w)};
            *(short4_t*)(xsb[cur ^ 1] + wbyte) = p;
        }
    }

    // epilogue: Q/K direct, V via LDS transpose
    const size_t grow0 = (size_t)row0 + mg * 16 + l4 * 4;
    const int col = cg * 16 + l15;
#pragma unroll
    for (int r = 0; r < 4; ++r) {
        Qg[(grow0 + r) * HS + col] = f2bf(acc0[r]);
        Kg[(grow0 + r) * HS + col] = f2bf(acc1[r]);
        Vs[mg * 16 + l4 * 4 + r][col] = acc2[r];
    }
    __syncthreads();
    const int vcol = t >> 3, vr0 = (t & 7) * 4;
    const int bb = row0 >> 12, s0 = row0 & 4095;
    short4_t vp = {(short)f2bf(Vs[vr0][vcol]),     (short)f2bf(Vs[vr0 + 1][vcol]),
                   (short)f2bf(Vs[vr0 + 2][vcol]), (short)f2bf(Vs[vr0 + 3][vcol])};
    *(short4_t*)(Vtg + ((size_t)bb * HS + vcol) * S_LEN + s0 + vr0) = vp;
}

// ---------------- MFMA flash attention, swapped operands, no K/V staging ----------------
// Block = 32 q-rows, 4 waves key-split (kb = w, w+4, ...). Per lane: col q = l15.
// S^T = mfma(K, Q^T); in-lane softmax (+2 shfl); P packed to LDS; O^T = mfma(V^T, P^T).
__global__ __launch_bounds__(256) void attn_kernel(
    const ushort_t* __restrict__ Qg, const ushort_t* __restrict__ Kg,
    const ushort_t* __restrict__ Vtg, float* __restrict__ out, int B)
{
    __shared__ char smem[34304];     // union: P 4x4KB | combine accb[4][32][65]f32 + mb/lb
    const int t    = threadIdx.x;
    const int w    = t >> 6;
    const int lane = t & 63;
    const int l15  = lane & 15;
    const int l4   = lane >> 4;

    const int b  = blockIdx.x % B;
    const int qt = (S_LEN / QB - 1) - (blockIdx.x / B);   // biggest tiles first
    const int q0 = qt * QB;
    const int ntiles = (q0 + QB + BK - 1) >> 6;

    char* myP = smem + w * 4096;     // [32 q][64 k] bf16, byte ^= ((row&7)<<4)
    const int psw = (l15 & 7) << 4;

    // Q B-fragments: qf[sub][c] = Qg[q0+sub*16+l15][c*32 + l4*8 ..+7]
    const ushort_t* Qbase = Qg + ((size_t)b * S_LEN + q0) * HS;
    short8 qf[2][2];
#pragma unroll
    for (int sub = 0; sub < 2; ++sub)
#pragma unroll
        for (int c = 0; c < 2; ++c)
            qf[sub][c] = *(const short8*)(Qbase + (sub * 16 + l15) * HS + c * 32 + l4 * 8);

    f32x4 acc[2][4];
#pragma unroll
    for (int i = 0; i < 2; ++i)
#pragma unroll
        for (int j = 0; j < 4; ++j) acc[i][j] = (f32x4){0.f,0.f,0.f,0.f};
    float m[2] = {-3e38f, -3e38f};
    float lsum[2] = {0.f, 0.f};

    const ushort_t* Kb = Kg  + (size_t)b * S_LEN * HS;
    const ushort_t* Vb = Vtg + (size_t)b * HS * S_LEN;

    for (int kb = w; kb < ntiles; kb += 4) {
        const int k0 = kb * BK;
        // K A-frags + V A-frags, direct from global (L2-resident)
        short8 kf[4][2], vf[4][2];
#pragma unroll
        for (int st = 0; st < 4; ++st)
#pragma unroll
            for (int c = 0; c < 2; ++c)
                kf[st][c] = *(const short8*)(Kb + (size_t)(k0 + st * 16 + l15) * HS + c * 32 + l4 * 8);
#pragma unroll
        for (int ds = 0; ds < 4; ++ds)
#pragma unroll
            for (int ks = 0; ks < 2; ++ks)
                vf[ds][ks] = *(const short8*)(Vb + (size_t)(ds * 16 + l15) * S_LEN + k0 + ks * 32 + l4 * 8);

        const bool lastTile = (kb == ntiles - 1);
#pragma unroll
        for (int sub = 0; sub < 2; ++sub) {
            // S^T[st]: lane holds S[key = k0+st*16+l4*4+r][q = q0+sub*16+l15]
            f32x4 sT[4];
#pragma unroll
            for (int st = 0; st < 4; ++st) {
                f32x4 z = (f32x4){0.f,0.f,0.f,0.f};
                z = __builtin_amdgcn_mfma_f32_16x16x32_bf16(kf[st][0], qf[sub][0], z, 0, 0, 0);
                z = __builtin_amdgcn_mfma_f32_16x16x32_bf16(kf[st][1], qf[sub][1], z, 0, 0, 0);
                sT[st] = z;
            }
            const int q = q0 + sub * 16 + l15;
#pragma unroll
            for (int st = 0; st < 4; ++st)
#pragma unroll
                for (int r = 0; r < 4; ++r) {
                    float sv = sT[st][r] * 0.125f;
                    if (lastTile && (k0 + st * 16 + l4 * 4 + r > q)) sv = -3e38f;
                    sT[st][r] = sv;
                }
            // row max: 15 in-lane fmax + 2 shfl
            float mt = sT[0][0];
#pragma unroll
            for (int st = 0; st < 4; ++st)
#pragma unroll
                for (int r = 0; r < 4; ++r) mt = fmaxf(mt, sT[st][r]);
            mt = fmaxf(mt, __shfl_xor(mt, 16));
            mt = fmaxf(mt, __shfl_xor(mt, 32));
            // defer-max rescale (THR=8)
            if (__any(mt > m[sub] + 8.f)) {
                float mn = fmaxf(m[sub], mt);
                float corr = __expf(m[sub] - mn);
                lsum[sub] *= corr;
#pragma unroll
                for (int ds = 0; ds < 4; ++ds)
#pragma unroll
                    for (int r = 0; r < 4; ++r) acc[sub][ds][r] *= corr;
                m[sub] = mn;
            }
            // P = exp(S - m), packed pairs -> LDS
            char* pr = myP + (sub * 16 + l15) * 128;
            float la = 0.f;
#pragma unroll
            for (int st = 0; st < 4; ++st)
#pragma unroll
                for (int h = 0; h < 4; h += 2) {
                    float p0 = __expf(sT[st][h]     - m[sub]);
                    float p1 = __expf(sT[st][h + 1] - m[sub]);
                    la += p0 + p1;
                    *(uint_t*)(pr + ((st * 32 + l4 * 8 + h * 2) ^ psw)) = cvt_pk_bf16(p0, p1);
                }
            lsum[sub] += la;
            // PV: O^T += V^T * P^T (same-wave LDS ordering; no barrier needed)
            short8 pb0 = *(const short8*)(pr + ((l4 * 16) ^ psw));
            short8 pb1 = *(const short8*)(pr + ((64 + l4 * 16) ^ psw));
#pragma unroll
            for (int ds = 0; ds < 4; ++ds) {
                acc[sub][ds] = __builtin_amdgcn_mfma_f32_16x16x32_bf16(vf[ds][0], pb0, acc[sub][ds], 0, 0, 0);
                acc[sub][ds] = __builtin_amdgcn_mfma_f32_16x16x32_bf16(vf[ds][1], pb1, acc[sub][ds], 0, 0, 0);
            }
        }
    }

    // l: sum the l4-slices (all share the same m per q)
#pragma unroll
    for (int sub = 0; sub < 2; ++sub) {
        lsum[sub] += __shfl_xor(lsum[sub], 16);
        lsum[sub] += __shfl_xor(lsum[sub], 32);
    }

    // in-block combine of 4 key-split partials
    __syncthreads();
    float* accb = (float*)smem;                       // [4][32][65]
    float* mb   = (float*)(smem + 4 * 32 * 65 * 4);   // [4][32]
    float* lb   = mb + 128;
#pragma unroll
    for (int sub = 0; sub < 2; ++sub) {
#pragma unroll
        for (int ds = 0; ds < 4; ++ds)
#pragma unroll
            for (int r = 0; r < 4; ++r)
                accb[(w * 32 + sub * 16 + l15) * 65 + ds * 16 + l4 * 4 + r] = acc[sub][ds][r];
        if (l4 == 0) {
            mb[w * 32 + sub * 16 + l15] = m[sub];
            lb[w * 32 + sub * 16 + l15] = lsum[sub];
        }
    }
    __syncthreads();

    const int d = t & 63;
#pragma unroll
    for (int pass = 0; pass < 8; ++pass) {
        const int row = (t >> 6) + pass * 4;          // 0..31
        float m0 = mb[row], m1 = mb[32 + row], m2 = mb[64 + row], m3 = mb[96 + row];
        float ms = fmaxf(fmaxf(m0, m1), fmaxf(m2, m3));
        float e0 = __expf(m0 - ms), e1 = __expf(m1 - ms), e2 = __expf(m2 - ms), e3 = __expf(m3 - ms);
        float o  = accb[(0 * 32 + row) * 65 + d] * e0 + accb[(1 * 32 + row) * 65 + d] * e1
                 + accb[(2 * 32 + row) * 65 + d] * e2 + accb[(3 * 32 + row) * 65 + d] * e3;
        float ll = lb[row] * e0 + lb[32 + row] * e1 + lb[64 + row] * e2 + lb[96 + row] * e3;
        out[((size_t)b * S_LEN + q0 + row) * HS + d] = o / ll;
    }
}

extern "C" void kernel_launch(void* const* d_in, const int* in_sizes, int n_in,
                              void* d_out, int out_size, void* d_ws, size_t ws_size,
                              hipStream_t stream) {
    const float* x  = (const float*)d_in[0];
    const float* Wq = (const float*)d_in[1];
    const float* Wk = (const float*)d_in[2];
    const float* Wv = (const float*)d_in[3];
    float* out = (float*)d_out;

    const int rows = in_sizes[0] / EMBD;   // B*S
    const int B    = rows / S_LEN;

    ushort_t* Qb = (ushort_t*)d_ws;
    ushort_t* Kb = Qb + (size_t)rows * HS;
    ushort_t* Vt = Kb + (size_t)rows * HS;
    ushort_t* Wt = Vt + (size_t)rows * HS;

    hipLaunchKernelGGL(wprep_kernel, dim3(36), dim3(256), 0, stream, Wq, Wk, Wv, Wt);
    hipLaunchKernelGGL(qkv_kernel, dim3(rows / 32), dim3(512), 0, stream,
                       x, Wt, Qb, Kb, Vt);
    hipLaunchKernelGGL(attn_kernel, dim3(B * (S_LEN / QB)), dim3(256), 0, stream,
                       Qb, Kb, Vt, out, B);
}